// Round 11
// baseline (93.816 us; speedup 1.0000x reference)
//
#include <hip/hip_runtime.h>
#include <math.h>

#define PH 7
#define PW 7
#define B_ 4
#define C_ 256
#define H_ 50
#define W_ 50
#define R_ 256
#define S_ (H_ * W_)     // 2500
#define NCELL (PH * PW)  // 49
#define THREADS 512

// SINGLE dispatch, reads features in the ORIGINAL (B,C,H,W) layout.
// Block = (batch b, channel c): the (b,c) plane is 10 KB -> staged in LDS
// with perfectly coalesced float4 loads (features read EXACTLY once,
// 10.24 MB total = the minimum). All window maxes are then LDS gathers.
// ~64 matching rois x 49 cells over 512 threads (~6 windows x ~12 px each).
// Why this beats R2's failed CHW kernel: R2 issued 71M scalar GLOBAL loads
// (issue-bound, 114 us); this issues 2.6M coalesced global loads + LDS
// gathers, 4 blocks/CU. Eliminates: transpose kernel, workspace, 1 of 2
// dispatches (R2 calibrated single-dispatch overhead ~6 us).
__global__ void __launch_bounds__(THREADS, 8)
roi_pool_plane(const float* __restrict__ features, const int* __restrict__ rois,
               float* __restrict__ out) {
    __shared__ __align__(16) float pl[S_];   // 10 KB plane
    __shared__ int4 geom[R_];                // x1,y1,h,w of matching rois
    __shared__ int  rlist[R_];               // their original indices
    __shared__ int  nmatch;

    const int bx = blockIdx.x;
    const int c  = bx & 255;                 // 0..255
    const int b  = bx >> 8;                  // 0..3
    const int tid = threadIdx.x;

    if (tid == 0) nmatch = 0;
    __syncthreads();

    // stage plane (625 float4, coalesced; plane base 10000B -> 16B aligned)
    {
        const float4* src = (const float4*)(features + ((size_t)b * C_ + c) * S_);
        float4* dst = (float4*)pl;
        #pragma unroll
        for (int i = tid; i < S_ / 4; i += THREADS) dst[i] = src[i];
    }

    // compact this batch's rois (order irrelevant -> LDS atomic)
    if (tid < R_) {
        const int* roi = rois + tid * 5;
        if (roi[0] == b) {
            const int x1 = roi[1] >> 4;      // floor(v/16), v in [0,800)
            const int y1 = roi[2] >> 4;
            const int x2 = roi[3] >> 4;
            const int y2 = roi[4] >> 4;
            const int pos = atomicAdd(&nmatch, 1);
            geom[pos]  = make_int4(x1, y1, y2 - y1 + 1, x2 - x1 + 1);
            rlist[pos] = tid;
        }
    }
    __syncthreads();

    // pairs i = j*49 + cell, j over matched rois. Consecutive lanes ->
    // consecutive cells of one roi: uniform-ish trip counts, and the
    // output addresses form contiguous 49-float runs (coalesced-ish).
    const int total = nmatch * NCELL;
    for (int i = tid; i < total; i += THREADS) {
        const int j    = i / NCELL;          // const divisor -> magic mul
        const int cell = i - j * NCELL;
        const int4 g   = geom[j];            // x1,y1,h,w
        const int ph   = cell / PW;          // magic mul
        const int pw   = cell - ph * PW;

        const int sh = g.y + (ph * g.z) / PH;
        const int eh = g.y + ((ph + 1) * g.z + PH - 1) / PH;   // <= y2+1 <= 50
        const int sw = g.x + (pw * g.w) / PW;
        const int ew = g.x + ((pw + 1) * g.w + PW - 1) / PW;   // <= x2+1 <= 50

        float m = -INFINITY;
        for (int y = sh; y < eh; ++y) {
            const float* prow = pl + y * W_;
            for (int x = sw; x < ew; ++x) m = fmaxf(m, prow[x]);
        }

        out[((size_t)rlist[j] * C_ + c) * NCELL + cell] = m;
    }
}

extern "C" void kernel_launch(void* const* d_in, const int* in_sizes, int n_in,
                              void* d_out, int out_size, void* d_ws, size_t ws_size,
                              hipStream_t stream) {
    const float* features = (const float*)d_in[0];
    const int*   rois     = (const int*)d_in[1];
    float*       out      = (float*)d_out;
    (void)d_ws; (void)ws_size;

    roi_pool_plane<<<B_ * C_, THREADS, 0, stream>>>(features, rois, out);
}